// Round 5
// baseline (223.449 us; speedup 1.0000x reference)
//
#include <hip/hip_runtime.h>
#include <hip/hip_bf16.h>

// DeepSeek MoE: D=FF=1024, E=8, top-2, T=4096 tokens, fp32 in/out, bf16 MFMA compute.

typedef short short8 __attribute__((ext_vector_type(8)));
typedef float f32x4  __attribute__((ext_vector_type(4)));

#define T_TOK 4096
#define NSLOT 8192
#define NWG   832   // worst-case live blocks: 256 shared + <=568 expert + pad; 832=8*104
#define CHUNK 104

// ---- workspace layout (bytes) ----
#define OFF_XB    (size_t)0                 // bf16 x        [4096][1024]  8 MB
#define OFF_W1T   (size_t)8388608           // bf16 w1^T     [8][1024][1024] 16 MB
#define OFF_W2T   (size_t)25165824          // bf16 w2^T     [8][1024][1024] 16 MB
#define OFF_SW1T  (size_t)41943040          // bf16 sw1^T    2 MB
#define OFF_SW2T  (size_t)44040192          // bf16 sw2^T    2 MB
#define OFF_HS    (size_t)46137344          // bf16 Hs       [4096][1024]  8 MB
#define OFF_HR    (size_t)54525952          // bf16 Hr       [9216][1024]  18 MB
#define OFF_META  (size_t)73400320          // counts[8], base[8]
#define OFF_ROWMAP (size_t)73400576         // int[9216]
#define OFF_ROWW  (size_t)73437440          // float[9216]
#define OFF_TKI   (size_t)73474304          // int[8192]
#define OFF_TKP   (size_t)73507072          // float[8192]

__device__ __forceinline__ unsigned short f2bf(float f) {
  __hip_bfloat16 h = __float2bfloat16(f);
  return __builtin_bit_cast(unsigned short, h);
}
__device__ __forceinline__ float gelu_exact(float x) {
  return 0.5f * x * (1.0f + erff(x * 0.70710678118654752f));
}

#define GLOAD16(g, l)                                                          \
  __builtin_amdgcn_global_load_lds(                                            \
      (const __attribute__((address_space(1))) void*)(g),                      \
      (__attribute__((address_space(3))) void*)(l), 16, 0, 0)

// ---------------- converts ----------------

// transpose+convert 1024x1024 fp32 matrices -> bf16 [n][k].
__global__ void k_transpose(const float* __restrict__ w1, const float* __restrict__ w2,
                            const float* __restrict__ sw1, const float* __restrict__ sw2,
                            unsigned short* __restrict__ w1t, unsigned short* __restrict__ w2t,
                            unsigned short* __restrict__ sw1t, unsigned short* __restrict__ sw2t) {
  __shared__ float tile[32][33];
  int z = blockIdx.z;
  const float* src; unsigned short* dst;
  if (z < 8)       { src = w1 + (size_t)z * 1048576;        dst = w1t + (size_t)z * 1048576; }
  else if (z < 16) { src = w2 + (size_t)(z - 8) * 1048576;  dst = w2t + (size_t)(z - 8) * 1048576; }
  else if (z == 16){ src = sw1; dst = sw1t; }
  else             { src = sw2; dst = sw2t; }
  int tx = threadIdx.x, ty = threadIdx.y;
  int gx = blockIdx.x * 32 + tx;
#pragma unroll
  for (int j = 0; j < 4; j++) {
    int gy = blockIdx.y * 32 + ty + j * 8;
    tile[ty + j * 8][tx] = src[(size_t)gy * 1024 + gx];
  }
  __syncthreads();
#pragma unroll
  for (int j = 0; j < 4; j++) {
    int orow = blockIdx.x * 32 + ty + j * 8;
    int ocol = blockIdx.y * 32 + tx;
    dst[(size_t)orow * 1024 + ocol] = f2bf(tile[tx][ty + j * 8]);
  }
}

__global__ void k_convert_x(const float* __restrict__ x, unsigned short* __restrict__ xb) {
  int i = blockIdx.x * blockDim.x + threadIdx.x;
  float4 v = ((const float4*)x)[i];
  ushort4 o;
  o.x = f2bf(v.x); o.y = f2bf(v.y); o.z = f2bf(v.z); o.w = f2bf(v.w);
  ((ushort4*)xb)[i] = o;
}

// ---------------- gating ----------------
__global__ void k_gate(const float* __restrict__ x, const float* __restrict__ gw,
                       const float* __restrict__ gb, int* __restrict__ tki,
                       float* __restrict__ tkp) {
  int wv = threadIdx.x >> 6, l = threadIdx.x & 63;
  int t = blockIdx.x * 4 + wv;
  float acc[8] = {0, 0, 0, 0, 0, 0, 0, 0};
  const float* xr = x + (size_t)t * 1024;
#pragma unroll
  for (int j = 0; j < 16; j++) {
    int k = j * 64 + l;
    float xv = xr[k];
    const float4* g4 = (const float4*)(gw + (size_t)k * 8);
    float4 ga = g4[0], gbv = g4[1];
    acc[0] += xv * ga.x; acc[1] += xv * ga.y; acc[2] += xv * ga.z; acc[3] += xv * ga.w;
    acc[4] += xv * gbv.x; acc[5] += xv * gbv.y; acc[6] += xv * gbv.z; acc[7] += xv * gbv.w;
  }
#pragma unroll
  for (int off = 32; off > 0; off >>= 1) {
#pragma unroll
    for (int e = 0; e < 8; e++) acc[e] += __shfl_xor(acc[e], off);
  }
  if (l == 0) {
    float lg[8], p[8];
    float m = -1e30f;
#pragma unroll
    for (int e = 0; e < 8; e++) { lg[e] = acc[e] + gb[e]; m = fmaxf(m, lg[e]); }
    float s = 0.f;
#pragma unroll
    for (int e = 0; e < 8; e++) { p[e] = expf(lg[e] - m); s += p[e]; }
    float inv = 1.0f / s;
#pragma unroll
    for (int e = 0; e < 8; e++) p[e] *= inv;
    int i0 = 0;
#pragma unroll
    for (int e = 1; e < 8; e++) if (p[e] > p[i0]) i0 = e;
    int i1 = (i0 == 0) ? 1 : 0;
#pragma unroll
    for (int e = 0; e < 8; e++) if (e != i0 && p[e] > p[i1]) i1 = e;
    tki[t * 2] = i0; tki[t * 2 + 1] = i1;
    tkp[t * 2] = p[i0]; tkp[t * 2 + 1] = p[i1];
  }
}

// fused count + plan + stable scatter (zero atomics, deterministic)
__global__ void k_route(const int* __restrict__ tki, const float* __restrict__ tkp,
                        int* __restrict__ counts, int* __restrict__ basev,
                        int* __restrict__ rowmap, float* __restrict__ roww) {
  int e = blockIdx.x, tid = threadIdx.x;
  int lane = tid & 63, wv = tid >> 6;
  int c[8] = {0, 0, 0, 0, 0, 0, 0, 0};
  for (int i = tid; i < NSLOT; i += 256) {
    int v = tki[i];
#pragma unroll
    for (int q = 0; q < 8; q++) c[q] += (v == q);
  }
  __shared__ int red[8][64];
#pragma unroll
  for (int q = 0; q < 8; q++) {
#pragma unroll
    for (int off = 32; off > 0; off >>= 1) c[q] += __shfl_xor(c[q], off);
  }
  if (lane == 0) {
#pragma unroll
    for (int q = 0; q < 8; q++) red[q][wv] = c[q];
  }
  __syncthreads();
  __shared__ int cnt_s[8], base_s[8];
  if (tid == 0) {
    int off = 0;
#pragma unroll
    for (int q = 0; q < 8; q++) {
      int cq = red[q][0] + red[q][1] + red[q][2] + red[q][3];
      cnt_s[q] = cq; base_s[q] = off;
      off += (cq + 127) & ~127;
    }
    counts[e] = cnt_s[e];
    basev[e] = base_s[e];
  }
  __syncthreads();
  __shared__ int warpsum[4];
  int wpos = base_s[e];
  for (int i0 = 0; i0 < NSLOT; i0 += 256) {
    int i = i0 + tid;
    bool pred = (tki[i] == e);
    unsigned long long mask = __ballot(pred);
    int wpre = __popcll(mask & ((1ull << lane) - 1));
    if (lane == 0) warpsum[wv] = __popcll(mask);
    __syncthreads();
    int wbase = 0;
    for (int w = 0; w < wv; w++) wbase += warpsum[w];
    int total = warpsum[0] + warpsum[1] + warpsum[2] + warpsum[3];
    if (pred) {
      int pos = wpos + wbase + wpre;
      rowmap[pos] = i >> 1;
      roww[pos] = tkp[i];
    }
    wpos += total;
    __syncthreads();
  }
}

// ---------------- fused FFN GEMM (2-phase prefetch, XCD-chunked 1-D grid) ----------------
// Work list W (z-major): [z=0 shared: 32y x 8x] then [e=0..7: ceil(cnt/128)y x 8x].
// Block bid -> W[(bid%8)*CHUNK + bid/8]  (keeps each XCD on few weight matrices).
// PHASE 1: H = gelu(A @ W1 + b1); PHASE 2: out += (p*) (H @ W2 + b2) atomically.
#define STAGE_TILE(buf, kk0)                                                   \
  {                                                                            \
    _Pragma("unroll") for (int i = 0; i < 4; i++) {                            \
      int q = i * 4 + wave;                                                    \
      int c = q * 64 + lane;                                                   \
      int m = c >> 3, s = c & 7;                                               \
      int ks = s ^ (m & 7);                                                    \
      GLOAD16(Amat + arow[i] * 1024 + (kk0) + ks * 8, &ldsA[buf][q * 512]);    \
    }                                                                          \
    _Pragma("unroll") for (int i = 0; i < 4; i++) {                            \
      int q = i * 4 + wave;                                                    \
      int c = q * 64 + lane;                                                   \
      int n = c >> 3, s = c & 7;                                               \
      int ks = s ^ (n & 7);                                                    \
      GLOAD16(Bmat + (size_t)(n0 + n) * 1024 + (kk0) + ks * 8,                 \
              &ldsB[buf][q * 512]);                                            \
    }                                                                          \
  }

template <int PHASE>
__global__ __launch_bounds__(256, 2) void k_ffn(
    const unsigned short* __restrict__ As,   // PHASE1: xb ; PHASE2: Hs
    const unsigned short* __restrict__ Ar,   // PHASE1: xb ; PHASE2: Hr
    const unsigned short* __restrict__ Bsh, const float* __restrict__ bsh,
    const unsigned short* __restrict__ Brt, const float* __restrict__ brt,
    unsigned short* __restrict__ Hsh, unsigned short* __restrict__ Hrt,
    float* __restrict__ outf,
    const int* __restrict__ rowmap, const float* __restrict__ roww,
    const int* __restrict__ counts, const int* __restrict__ bases) {
  __shared__ unsigned short ldsA[2][128 * 64];
  __shared__ unsigned short ldsB[2][128 * 64];

  // XCD-chunked work decode
  int bid = blockIdx.x;
  int j = (bid & 7) * CHUNK + (bid >> 3);
  int z = -1, rel = j;
  if (rel < 256) {
    z = 0;
  } else {
    rel -= 256;
#pragma unroll
    for (int e = 0; e < 8; e++) {
      int nye = ((counts[e] + 127) >> 7) << 3;  // live (y,x) entries for expert e
      if (z < 0) {
        if (rel < nye) z = e + 1; else rel -= nye;
      }
    }
    if (z < 0) return;
  }
  int row0 = (rel >> 3) * 128;
  int n0 = (rel & 7) * 128;

  int nrows, rbase = 0;
  const unsigned short* Bmat; const float* bvec; const unsigned short* Amat;
  if (z == 0) {
    nrows = T_TOK; Bmat = Bsh; bvec = bsh; Amat = As;
  } else {
    int e = z - 1;
    nrows = counts[e]; rbase = bases[e];
    Bmat = Brt + (size_t)e * 1048576;
    bvec = brt + (size_t)e * 1024;
    Amat = (PHASE == 1) ? As : Ar;
  }
  int tid = threadIdx.x, wave = tid >> 6, lane = tid & 63;
  int wm = wave >> 1, wn = wave & 1;

  // hoist A staging row indices (gather resolved once)
  long arow[4];
#pragma unroll
  for (int i = 0; i < 4; i++) {
    int q = i * 4 + wave;
    int m = (q * 64 + lane) >> 3;
    int r = row0 + m;
    if (r >= nrows) r = nrows - 1;
    if (z == 0)            arow[i] = r;
    else if (PHASE == 1)   arow[i] = rowmap[rbase + r];
    else                   arow[i] = rbase + r;
  }

  f32x4 acc[4][4];
#pragma unroll
  for (int i = 0; i < 4; i++)
#pragma unroll
    for (int j2 = 0; j2 < 4; j2++) acc[i][j2] = (f32x4){0.f, 0.f, 0.f, 0.f};

  // prologue: tile 0 into buffer 0
  STAGE_TILE(0, 0);
  __syncthreads();

#pragma unroll 2
  for (int t = 0; t < 16; ++t) {
    int b = t & 1;
    if (t < 15) STAGE_TILE(b ^ 1, (t + 1) * 64);  // prefetch next (in flight during compute)
#pragma unroll
    for (int kk = 0; kk < 2; kk++) {
      short8 af[4], bfr[4];
      int kc0 = kk * 4 + (lane >> 4);
#pragma unroll
      for (int fi = 0; fi < 4; fi++) {
        int m = wm * 64 + fi * 16 + (lane & 15);
        int slot = kc0 ^ (m & 7);
        af[fi] = *(const short8*)&ldsA[b][m * 64 + slot * 8];
      }
#pragma unroll
      for (int fj = 0; fj < 4; fj++) {
        int n = wn * 64 + fj * 16 + (lane & 15);
        int slot = kc0 ^ (n & 7);
        bfr[fj] = *(const short8*)&ldsB[b][n * 64 + slot * 8];
      }
#pragma unroll
      for (int fi = 0; fi < 4; fi++)
#pragma unroll
        for (int fj = 0; fj < 4; fj++)
          acc[fi][fj] = __builtin_amdgcn_mfma_f32_16x16x32_bf16(af[fi], bfr[fj], acc[fi][fj], 0, 0, 0);
    }
    __syncthreads();  // drains prefetch (vmcnt 0) + protects buffer reuse
  }

  // epilogue: frag row = (lane>>4)*4 + rg, col = lane&15
#pragma unroll
  for (int fi = 0; fi < 4; fi++) {
#pragma unroll
    for (int rg = 0; rg < 4; rg++) {
      int lr = wm * 64 + fi * 16 + (lane >> 4) * 4 + rg;
      int r = row0 + lr;
      if (r >= nrows) continue;
      if (PHASE == 1) {
        unsigned short* dst = (z == 0) ? (Hsh + (size_t)r * 1024)
                                       : (Hrt + (size_t)(rbase + r) * 1024);
#pragma unroll
        for (int fj = 0; fj < 4; fj++) {
          int col = n0 + wn * 64 + fj * 16 + (lane & 15);
          dst[col] = f2bf(gelu_exact(acc[fi][fj][rg] + bvec[col]));
        }
      } else {
        if (z == 0) {
#pragma unroll
          for (int fj = 0; fj < 4; fj++) {
            int col = n0 + wn * 64 + fj * 16 + (lane & 15);
            atomicAdd(&outf[(size_t)r * 1024 + col], acc[fi][fj][rg] + bvec[col]);
          }
        } else {
          int tok = rowmap[rbase + r];
          float p = roww[rbase + r];
#pragma unroll
          for (int fj = 0; fj < 4; fj++) {
            int col = n0 + wn * 64 + fj * 16 + (lane & 15);
            atomicAdd(&outf[(size_t)tok * 1024 + col], p * (acc[fi][fj][rg] + bvec[col]));
          }
        }
      }
    }
  }
}

extern "C" void kernel_launch(void* const* d_in, const int* in_sizes, int n_in,
                              void* d_out, int out_size, void* d_ws, size_t ws_size,
                              hipStream_t stream) {
  const float* x   = (const float*)d_in[0];
  const float* gw  = (const float*)d_in[1];
  const float* gb  = (const float*)d_in[2];
  const float* sw1 = (const float*)d_in[3];
  const float* sb1 = (const float*)d_in[4];
  const float* sw2 = (const float*)d_in[5];
  const float* sb2 = (const float*)d_in[6];
  const float* w1  = (const float*)d_in[7];
  const float* b1  = (const float*)d_in[8];
  const float* w2  = (const float*)d_in[9];
  const float* b2  = (const float*)d_in[10];
  float* out = (float*)d_out;
  char* ws = (char*)d_ws;

  unsigned short* xb   = (unsigned short*)(ws + OFF_XB);
  unsigned short* w1t  = (unsigned short*)(ws + OFF_W1T);
  unsigned short* w2t  = (unsigned short*)(ws + OFF_W2T);
  unsigned short* sw1t = (unsigned short*)(ws + OFF_SW1T);
  unsigned short* sw2t = (unsigned short*)(ws + OFF_SW2T);
  unsigned short* Hs   = (unsigned short*)(ws + OFF_HS);
  unsigned short* Hr   = (unsigned short*)(ws + OFF_HR);
  int*   counts = (int*)(ws + OFF_META);
  int*   basev  = counts + 8;
  int*   rowmap = (int*)(ws + OFF_ROWMAP);
  float* roww   = (float*)(ws + OFF_ROWW);
  int*   tki    = (int*)(ws + OFF_TKI);
  float* tkp    = (float*)(ws + OFF_TKP);

  hipMemsetAsync(out, 0, (size_t)out_size * sizeof(float), stream);
  k_transpose<<<dim3(32, 32, 18), dim3(32, 8), 0, stream>>>(w1, w2, sw1, sw2, w1t, w2t, sw1t, sw2t);
  k_convert_x<<<4096, 256, 0, stream>>>(x, xb);
  k_gate<<<1024, 256, 0, stream>>>(x, gw, gb, tki, tkp);
  k_route<<<8, 256, 0, stream>>>(tki, tkp, counts, basev, rowmap, roww);

  // FFN1: shared + 8 routed experts, one 1-D launch
  k_ffn<1><<<NWG, 256, 0, stream>>>(xb, xb, sw1t, sb1, w1t, b1, Hs, Hr,
                                    nullptr, rowmap, roww, counts, basev);
  // FFN2: shared + routed, atomic into pre-zeroed out
  k_ffn<2><<<NWG, 256, 0, stream>>>(Hs, Hr, sw2t, sb2, w2t, b2, nullptr, nullptr,
                                    out, rowmap, roww, counts, basev);
}

// Round 6
// 186.307 us; speedup vs baseline: 1.1994x; 1.1994x over previous
//
#include <hip/hip_runtime.h>
#include <hip/hip_bf16.h>

// DeepSeek MoE: D=FF=1024, E=8, top-2, T=4096 tokens, fp32 in/out, bf16 MFMA compute.

typedef short short8 __attribute__((ext_vector_type(8)));
typedef float f32x4  __attribute__((ext_vector_type(4)));

#define T_TOK 4096
#define NSLOT 8192
#define NWG   832   // worst-case live blocks: 256 shared + 576 expert entries
#define CHUNK 104

// ---- workspace layout (bytes) ----
#define OFF_XB    (size_t)0                 // bf16 x        [4096][1024]  8 MB
#define OFF_W1T   (size_t)8388608           // bf16 w1^T     [8][1024][1024] 16 MB
#define OFF_W2T   (size_t)25165824          // bf16 w2^T     [8][1024][1024] 16 MB
#define OFF_SW1T  (size_t)41943040          // bf16 sw1^T    2 MB
#define OFF_SW2T  (size_t)44040192          // bf16 sw2^T    2 MB
#define OFF_HS    (size_t)46137344          // bf16 Hs       [4096][1024]  8 MB
#define OFF_HR    (size_t)54525952          // bf16 Hr       [9216][1024]  18 MB
#define OFF_META  (size_t)73400320          // counts[8], base[8]
#define OFF_ROWMAP (size_t)73400576         // int[9216]
#define OFF_ROWW  (size_t)73437440          // float[9216]
#define OFF_TKI   (size_t)73474304          // int[8192]
#define OFF_TKP   (size_t)73507072          // float[8192]

__device__ __forceinline__ unsigned short f2bf(float f) {
  __hip_bfloat16 h = __float2bfloat16(f);
  return __builtin_bit_cast(unsigned short, h);
}
__device__ __forceinline__ float gelu_exact(float x) {
  return 0.5f * x * (1.0f + erff(x * 0.70710678118654752f));
}

#define GLOAD16(g, l)                                                          \
  __builtin_amdgcn_global_load_lds(                                            \
      (const __attribute__((address_space(1))) void*)(g),                      \
      (__attribute__((address_space(3))) void*)(l), 16, 0, 0)

// ---------------- converts ----------------

__global__ void k_transpose(const float* __restrict__ w1, const float* __restrict__ w2,
                            const float* __restrict__ sw1, const float* __restrict__ sw2,
                            unsigned short* __restrict__ w1t, unsigned short* __restrict__ w2t,
                            unsigned short* __restrict__ sw1t, unsigned short* __restrict__ sw2t) {
  __shared__ float tile[32][33];
  int z = blockIdx.z;
  const float* src; unsigned short* dst;
  if (z < 8)       { src = w1 + (size_t)z * 1048576;        dst = w1t + (size_t)z * 1048576; }
  else if (z < 16) { src = w2 + (size_t)(z - 8) * 1048576;  dst = w2t + (size_t)(z - 8) * 1048576; }
  else if (z == 16){ src = sw1; dst = sw1t; }
  else             { src = sw2; dst = sw2t; }
  int tx = threadIdx.x, ty = threadIdx.y;
  int gx = blockIdx.x * 32 + tx;
#pragma unroll
  for (int j = 0; j < 4; j++) {
    int gy = blockIdx.y * 32 + ty + j * 8;
    tile[ty + j * 8][tx] = src[(size_t)gy * 1024 + gx];
  }
  __syncthreads();
#pragma unroll
  for (int j = 0; j < 4; j++) {
    int orow = blockIdx.x * 32 + ty + j * 8;
    int ocol = blockIdx.y * 32 + tx;
    dst[(size_t)orow * 1024 + ocol] = f2bf(tile[tx][ty + j * 8]);
  }
}

__global__ void k_convert_x(const float* __restrict__ x, unsigned short* __restrict__ xb) {
  int i = blockIdx.x * blockDim.x + threadIdx.x;
  float4 v = ((const float4*)x)[i];
  ushort4 o;
  o.x = f2bf(v.x); o.y = f2bf(v.y); o.z = f2bf(v.z); o.w = f2bf(v.w);
  ((ushort4*)xb)[i] = o;
}

// ---------------- gating ----------------
__global__ void k_gate(const float* __restrict__ x, const float* __restrict__ gw,
                       const float* __restrict__ gb, int* __restrict__ tki,
                       float* __restrict__ tkp) {
  int wv = threadIdx.x >> 6, l = threadIdx.x & 63;
  int t = blockIdx.x * 4 + wv;
  float acc[8] = {0, 0, 0, 0, 0, 0, 0, 0};
  const float* xr = x + (size_t)t * 1024;
#pragma unroll
  for (int j = 0; j < 16; j++) {
    int k = j * 64 + l;
    float xv = xr[k];
    const float4* g4 = (const float4*)(gw + (size_t)k * 8);
    float4 ga = g4[0], gbv = g4[1];
    acc[0] += xv * ga.x; acc[1] += xv * ga.y; acc[2] += xv * ga.z; acc[3] += xv * ga.w;
    acc[4] += xv * gbv.x; acc[5] += xv * gbv.y; acc[6] += xv * gbv.z; acc[7] += xv * gbv.w;
  }
#pragma unroll
  for (int off = 32; off > 0; off >>= 1) {
#pragma unroll
    for (int e = 0; e < 8; e++) acc[e] += __shfl_xor(acc[e], off);
  }
  if (l == 0) {
    float lg[8], p[8];
    float m = -1e30f;
#pragma unroll
    for (int e = 0; e < 8; e++) { lg[e] = acc[e] + gb[e]; m = fmaxf(m, lg[e]); }
    float s = 0.f;
#pragma unroll
    for (int e = 0; e < 8; e++) { p[e] = expf(lg[e] - m); s += p[e]; }
    float inv = 1.0f / s;
#pragma unroll
    for (int e = 0; e < 8; e++) p[e] *= inv;
    int i0 = 0;
#pragma unroll
    for (int e = 1; e < 8; e++) if (p[e] > p[i0]) i0 = e;
    int i1 = (i0 == 0) ? 1 : 0;
#pragma unroll
    for (int e = 0; e < 8; e++) if (e != i0 && p[e] > p[i1]) i1 = e;
    tki[t * 2] = i0; tki[t * 2 + 1] = i1;
    tkp[t * 2] = p[i0]; tkp[t * 2 + 1] = p[i1];
  }
}

// fused count + plan + stable scatter (zero atomics, deterministic)
__global__ void k_route(const int* __restrict__ tki, const float* __restrict__ tkp,
                        int* __restrict__ counts, int* __restrict__ basev,
                        int* __restrict__ rowmap, float* __restrict__ roww) {
  int e = blockIdx.x, tid = threadIdx.x;
  int lane = tid & 63, wv = tid >> 6;
  int c[8] = {0, 0, 0, 0, 0, 0, 0, 0};
  for (int i = tid; i < NSLOT; i += 256) {
    int v = tki[i];
#pragma unroll
    for (int q = 0; q < 8; q++) c[q] += (v == q);
  }
  __shared__ int red[8][64];
#pragma unroll
  for (int q = 0; q < 8; q++) {
#pragma unroll
    for (int off = 32; off > 0; off >>= 1) c[q] += __shfl_xor(c[q], off);
  }
  if (lane == 0) {
#pragma unroll
    for (int q = 0; q < 8; q++) red[q][wv] = c[q];
  }
  __syncthreads();
  __shared__ int cnt_s[8], base_s[8];
  if (tid == 0) {
    int off = 0;
#pragma unroll
    for (int q = 0; q < 8; q++) {
      int cq = red[q][0] + red[q][1] + red[q][2] + red[q][3];
      cnt_s[q] = cq; base_s[q] = off;
      off += (cq + 127) & ~127;
    }
    counts[e] = cnt_s[e];
    basev[e] = base_s[e];
  }
  __syncthreads();
  __shared__ int warpsum[4];
  int wpos = base_s[e];
  for (int i0 = 0; i0 < NSLOT; i0 += 256) {
    int i = i0 + tid;
    bool pred = (tki[i] == e);
    unsigned long long mask = __ballot(pred);
    int wpre = __popcll(mask & ((1ull << lane) - 1));
    if (lane == 0) warpsum[wv] = __popcll(mask);
    __syncthreads();
    int wbase = 0;
    for (int w = 0; w < wv; w++) wbase += warpsum[w];
    int total = warpsum[0] + warpsum[1] + warpsum[2] + warpsum[3];
    if (pred) {
      int pos = wpos + wbase + wpre;
      rowmap[pos] = i >> 1;
      roww[pos] = tkp[i];
    }
    wpos += total;
    __syncthreads();
  }
}

// ---------------- fused FFN GEMM (single-buffer m97 loop, XCD-chunked 1-D grid) ----------------
// Work list W (z-major): [z=0 shared: 32y x 8x] then [e=0..7: ceil(cnt/128)y x 8x].
// Block bid -> W[(bid%8)*CHUNK + bid/8]  (keeps each XCD on few weight matrices).
template <int PHASE>
__global__ __launch_bounds__(256, 4) void k_ffn(
    const unsigned short* __restrict__ As,   // PHASE1: xb ; PHASE2: Hs
    const unsigned short* __restrict__ Ar,   // PHASE1: xb ; PHASE2: Hr
    const unsigned short* __restrict__ Bsh, const float* __restrict__ bsh,
    const unsigned short* __restrict__ Brt, const float* __restrict__ brt,
    unsigned short* __restrict__ Hsh, unsigned short* __restrict__ Hrt,
    float* __restrict__ outf,
    const int* __restrict__ rowmap, const float* __restrict__ roww,
    const int* __restrict__ counts, const int* __restrict__ bases) {
  __shared__ unsigned short ldsA[128 * 64];
  __shared__ unsigned short ldsB[128 * 64];

  // XCD-chunked work decode
  int bid = blockIdx.x;
  int j = (bid & 7) * CHUNK + (bid >> 3);
  int z = -1, rel = j;
  if (rel < 256) {
    z = 0;
  } else {
    rel -= 256;
#pragma unroll
    for (int e = 0; e < 8; e++) {
      int nye = ((counts[e] + 127) >> 7) << 3;  // live (y,x) entries for expert e
      if (z < 0) {
        if (rel < nye) z = e + 1; else rel -= nye;
      }
    }
    if (z < 0) return;
  }
  int row0 = (rel >> 3) * 128;
  int n0 = (rel & 7) * 128;

  int nrows, rbase = 0;
  const unsigned short* Bmat; const float* bvec; const unsigned short* Amat;
  if (z == 0) {
    nrows = T_TOK; Bmat = Bsh; bvec = bsh; Amat = As;
  } else {
    int e = z - 1;
    nrows = counts[e]; rbase = bases[e];
    Bmat = Brt + (size_t)e * 1048576;
    bvec = brt + (size_t)e * 1024;
    Amat = (PHASE == 1) ? As : Ar;
  }
  int tid = threadIdx.x, wave = tid >> 6, lane = tid & 63;
  int wm = wave >> 1, wn = wave & 1;

  // hoist A staging row indices (gather resolved once)
  long arow[4];
#pragma unroll
  for (int i = 0; i < 4; i++) {
    int q = i * 4 + wave;
    int m = (q * 64 + lane) >> 3;
    int r = row0 + m;
    if (r >= nrows) r = nrows - 1;
    if (z == 0)            arow[i] = r;
    else if (PHASE == 1)   arow[i] = rowmap[rbase + r];
    else                   arow[i] = rbase + r;
  }

  f32x4 acc[4][4];
#pragma unroll
  for (int i = 0; i < 4; i++)
#pragma unroll
    for (int j2 = 0; j2 < 4; j2++) acc[i][j2] = (f32x4){0.f, 0.f, 0.f, 0.f};

  for (int k0 = 0; k0 < 1024; k0 += 64) {
    // stage A: 128 rows x 64 k, XOR-swizzled on the SOURCE side
#pragma unroll
    for (int i = 0; i < 4; i++) {
      int q = i * 4 + wave;
      int c = q * 64 + lane;
      int m = c >> 3, s = c & 7;
      int ks = s ^ (m & 7);
      GLOAD16(Amat + arow[i] * 1024 + k0 + ks * 8, &ldsA[q * 512]);
    }
    // stage B: 128 rows x 64 k
#pragma unroll
    for (int i = 0; i < 4; i++) {
      int q = i * 4 + wave;
      int c = q * 64 + lane;
      int n = c >> 3, s = c & 7;
      int ks = s ^ (n & 7);
      GLOAD16(Bmat + (size_t)(n0 + n) * 1024 + k0 + ks * 8, &ldsB[q * 512]);
    }
    __syncthreads();
#pragma unroll
    for (int kk = 0; kk < 2; kk++) {
      short8 af[4], bfr[4];
      int kc0 = kk * 4 + (lane >> 4);
#pragma unroll
      for (int fi = 0; fi < 4; fi++) {
        int m = wm * 64 + fi * 16 + (lane & 15);
        int slot = kc0 ^ (m & 7);
        af[fi] = *(const short8*)&ldsA[m * 64 + slot * 8];
      }
#pragma unroll
      for (int fj = 0; fj < 4; fj++) {
        int n = wn * 64 + fj * 16 + (lane & 15);
        int slot = kc0 ^ (n & 7);
        bfr[fj] = *(const short8*)&ldsB[n * 64 + slot * 8];
      }
#pragma unroll
      for (int fi = 0; fi < 4; fi++)
#pragma unroll
        for (int fj = 0; fj < 4; fj++)
          acc[fi][fj] = __builtin_amdgcn_mfma_f32_16x16x32_bf16(af[fi], bfr[fj], acc[fi][fj], 0, 0, 0);
    }
    __syncthreads();
  }

  // epilogue: frag row = (lane>>4)*4 + rg, col = lane&15
#pragma unroll
  for (int fi = 0; fi < 4; fi++) {
#pragma unroll
    for (int rg = 0; rg < 4; rg++) {
      int lr = wm * 64 + fi * 16 + (lane >> 4) * 4 + rg;
      int r = row0 + lr;
      if (r >= nrows) continue;
      if (PHASE == 1) {
        unsigned short* dst = (z == 0) ? (Hsh + (size_t)r * 1024)
                                       : (Hrt + (size_t)(rbase + r) * 1024);
#pragma unroll
        for (int fj = 0; fj < 4; fj++) {
          int col = n0 + wn * 64 + fj * 16 + (lane & 15);
          dst[col] = f2bf(gelu_exact(acc[fi][fj][rg] + bvec[col]));
        }
      } else {
        if (z == 0) {
#pragma unroll
          for (int fj = 0; fj < 4; fj++) {
            int col = n0 + wn * 64 + fj * 16 + (lane & 15);
            atomicAdd(&outf[(size_t)r * 1024 + col], acc[fi][fj][rg] + bvec[col]);
          }
        } else {
          int tok = rowmap[rbase + r];
          float p = roww[rbase + r];
#pragma unroll
          for (int fj = 0; fj < 4; fj++) {
            int col = n0 + wn * 64 + fj * 16 + (lane & 15);
            atomicAdd(&outf[(size_t)tok * 1024 + col], p * (acc[fi][fj][rg] + bvec[col]));
          }
        }
      }
    }
  }
}

extern "C" void kernel_launch(void* const* d_in, const int* in_sizes, int n_in,
                              void* d_out, int out_size, void* d_ws, size_t ws_size,
                              hipStream_t stream) {
  const float* x   = (const float*)d_in[0];
  const float* gw  = (const float*)d_in[1];
  const float* gb  = (const float*)d_in[2];
  const float* sw1 = (const float*)d_in[3];
  const float* sb1 = (const float*)d_in[4];
  const float* sw2 = (const float*)d_in[5];
  const float* sb2 = (const float*)d_in[6];
  const float* w1  = (const float*)d_in[7];
  const float* b1  = (const float*)d_in[8];
  const float* w2  = (const float*)d_in[9];
  const float* b2  = (const float*)d_in[10];
  float* out = (float*)d_out;
  char* ws = (char*)d_ws;

  unsigned short* xb   = (unsigned short*)(ws + OFF_XB);
  unsigned short* w1t  = (unsigned short*)(ws + OFF_W1T);
  unsigned short* w2t  = (unsigned short*)(ws + OFF_W2T);
  unsigned short* sw1t = (unsigned short*)(ws + OFF_SW1T);
  unsigned short* sw2t = (unsigned short*)(ws + OFF_SW2T);
  unsigned short* Hs   = (unsigned short*)(ws + OFF_HS);
  unsigned short* Hr   = (unsigned short*)(ws + OFF_HR);
  int*   counts = (int*)(ws + OFF_META);
  int*   basev  = counts + 8;
  int*   rowmap = (int*)(ws + OFF_ROWMAP);
  float* roww   = (float*)(ws + OFF_ROWW);
  int*   tki    = (int*)(ws + OFF_TKI);
  float* tkp    = (float*)(ws + OFF_TKP);

  hipMemsetAsync(out, 0, (size_t)out_size * sizeof(float), stream);
  k_transpose<<<dim3(32, 32, 18), dim3(32, 8), 0, stream>>>(w1, w2, sw1, sw2, w1t, w2t, sw1t, sw2t);
  k_convert_x<<<4096, 256, 0, stream>>>(x, xb);
  k_gate<<<1024, 256, 0, stream>>>(x, gw, gb, tki, tkp);
  k_route<<<8, 256, 0, stream>>>(tki, tkp, counts, basev, rowmap, roww);

  // FFN1: shared + 8 routed experts, one 1-D launch
  k_ffn<1><<<NWG, 256, 0, stream>>>(xb, xb, sw1t, sb1, w1t, b1, Hs, Hr,
                                    nullptr, rowmap, roww, counts, basev);
  // FFN2: shared + routed, atomic into pre-zeroed out
  k_ffn<2><<<NWG, 256, 0, stream>>>(Hs, Hr, sw2t, sb2, w2t, b2, nullptr, nullptr,
                                    out, rowmap, roww, counts, basev);
}